// Round 6
// baseline (302.321 us; speedup 1.0000x reference)
//
#include <hip/hip_runtime.h>
#include <hip/hip_bf16.h>
#include <math.h>

#define D_STATE   64
#define HEADDIM   64
#define D_INNER   2048
#define NHEADS    32
#define GN        64
#define CONV_DIM  2304
#define D_IN_PROJ 4416
#define ZLD       4352      /* z + xBC columns only (dt handled separately) */
#define K_SP      7
#define K_TP      4
#define CHUNK     256
#define BATCHN    2
#define FRAMES    8
#define SPATIAL   256
#define SEQLEN    2048
#define NCH       8
#define MTOT      4096

typedef __attribute__((ext_vector_type(8))) short short8;
typedef __attribute__((ext_vector_type(8))) unsigned short ushort8v;
typedef __attribute__((ext_vector_type(4))) float floatx4;

__device__ __forceinline__ float silu_f(float x) { return x / (1.f + __expf(-x)); }
__device__ __forceinline__ int flip_l(int l) { return (l & ~7) | (7 - (l & 7)); }
__device__ __forceinline__ unsigned short f2bf(float f) {
  unsigned int u = __float_as_uint(f);
  unsigned int r = (u + 0x7fffu + ((u >> 16) & 1u)) >> 16;
  return (unsigned short)r;
}
__device__ __forceinline__ float bf2f(unsigned short s) {
  return __uint_as_float(((unsigned int)s) << 16);
}
__device__ __forceinline__ unsigned int cvtpk_bf16(float lo, float hi) {
  unsigned int r;
  asm("v_cvt_pk_bf16_f32 %0, %1, %2" : "=v"(r) : "v"(lo), "v"(hi));
  return r;
}
typedef union { short8 v; unsigned int u[4]; } s8u;
__device__ __forceinline__ void gload_lds16(const unsigned short* g, unsigned short* l) {
  __builtin_amdgcn_global_load_lds((const __attribute__((address_space(1))) void*)g,
                                   (__attribute__((address_space(3))) void*)l, 16, 0, 0);
}

// ---------------- f32 -> bf16 cast (four tensors, one launch) ----------------
__global__ __launch_bounds__(256) void cast4_bf16_kernel(const float* __restrict__ a,
                                                         unsigned short* __restrict__ oa,
                                                         int na,
                                                         const float* __restrict__ b,
                                                         unsigned short* __restrict__ ob,
                                                         int nb,
                                                         const float* __restrict__ c,
                                                         unsigned short* __restrict__ oc,
                                                         int nc,
                                                         const float* __restrict__ d,
                                                         unsigned short* __restrict__ od) {
  int bid = blockIdx.x;
  const float* in;
  unsigned short* out;
  size_t blk;
  if (bid < na)                 { in = a; out = oa; blk = bid; }
  else if (bid < na + nb)       { in = b; out = ob; blk = bid - na; }
  else if (bid < na + nb + nc)  { in = c; out = oc; blk = bid - na - nb; }
  else                          { in = d; out = od; blk = bid - na - nb - nc; }
  size_t i = (blk * 256 + threadIdx.x) * 4;
  float4 v = *(const float4*)(in + i);
  ushort4 o;
  o.x = f2bf(v.x); o.y = f2bf(v.y); o.z = f2bf(v.z); o.w = f2bf(v.w);
  *(ushort4*)(out + i) = o;
}

// ---------------- tall-skinny MFMA GEMM body: C[M x N] = A(bf16) @ B(bf16)^T ----------------
__device__ __forceinline__ void ts_body_bf16(const unsigned short* __restrict__ A, int lda,
                                             const unsigned short* __restrict__ B, int ldb,
                                             float* __restrict__ C, int ldc, int N, int K,
                                             int m0, float* red) {
  const int tid = threadIdx.x;
  const int lane = tid & 63;
  const int w = tid >> 6;
  const int fr = lane & 15;
  const int kq = (lane >> 4) * 8;
  const int nt = N >> 4;
  const int kseg = K >> 2;
  const int k0 = w * kseg;
  floatx4 acc[4] = {};
  for (int k = k0; k < k0 + kseg; k += 32) {
    short8 af = *(const short8*)(A + (size_t)(m0 + fr) * lda + k + kq);
    for (int j = 0; j < nt; ++j) {
      short8 bf8 = *(const short8*)(B + (size_t)(j * 16 + fr) * ldb + k + kq);
      acc[j] = __builtin_amdgcn_mfma_f32_16x16x32_bf16(af, bf8, acc[j], 0, 0, 0);
    }
  }
  const int rg = (lane >> 4) * 4;
  for (int j = 0; j < nt; ++j)
#pragma unroll
    for (int q = 0; q < 4; ++q)
      red[w * 1024 + j * 256 + (rg + q) * 16 + fr] = acc[j][q];
  __syncthreads();
  const int entries = nt * 256;
  for (int e = tid; e < entries; e += 256) {
    float s = red[e] + red[1024 + e] + red[2048 + e] + red[3072 + e];
    int j = e >> 8, idx = e & 255, row = idx >> 4, col = idx & 15;
    C[(size_t)(m0 + row) * ldc + j * 16 + col] = s;
  }
}

// ---- merged: in_proj GEMM (blocks 0..1087, 128x128, XCD-region swizzle) +
//      dt tall-skinny GEMM (blocks 1088..1343) — both depend only on cast4;
//      the short ts blocks pad the GEMM drain tail. ----
__global__ __launch_bounds__(256) void gemm_main_kernel(
    const unsigned short* __restrict__ A, int lda,
    const unsigned short* __restrict__ B, int ldb,
    unsigned short* __restrict__ C, int ldc, int K,
    const unsigned short* __restrict__ Bdt, float* __restrict__ DTraw) {
  __shared__ __align__(16) char smem[32768];
  const int tid = threadIdx.x;
  const int lane = tid & 63;
  const int w = tid >> 6;
  if (blockIdx.x >= 1088) {
    ts_body_bf16(A, lda, Bdt, lda, DTraw, 64, 64, K,
                 (blockIdx.x - 1088) * 16, (float*)smem);
    return;
  }
  unsigned short* As = (unsigned short*)smem;     // 128*64
  unsigned short* Bs = As + 128 * 64;             // 128*64
  const int bid = blockIdx.x;
  const int xcd = bid & 7;
  const int rp  = bid >> 3;          // 0..135
  const int px  = rp % 17;
  const int py  = rp / 17;           // 0..7
  const int m0 = ((xcd >> 1) * 8 + py) * 128;
  const int n0 = ((xcd & 1) * 17 + px) * 128;
  const int wm = (w >> 1) * 64;
  const int wn = (w & 1) * 64;
  const int lrow = lane >> 3;            // 0..7 within 8-row group
  const int lperm = lane & 7;            // LDS slot within row
  floatx4 acc[4][4] = {};
  for (int k0 = 0; k0 < K; k0 += 64) {
#pragma unroll
    for (int j = 0; j < 8; ++j) {
      int g = j * 4 + w;                 // 0..31: 16 A-groups then 16 B-groups
      if (g < 16) {
        int row = g * 8 + lrow;
        int cg = (lperm ^ (row & 7)) * 8;
        gload_lds16(A + (size_t)(m0 + row) * lda + k0 + cg, &As[g * 512]);
      } else {
        int gb = g - 16;
        int row = gb * 8 + lrow;
        int cg = (lperm ^ (row & 7)) * 8;
        gload_lds16(B + (size_t)(n0 + row) * ldb + k0 + cg, &Bs[gb * 512]);
      }
    }
    __syncthreads();
    const int fr = lane & 15;
    const int kq = (lane >> 4) * 8;
#pragma unroll
    for (int kk = 0; kk < 64; kk += 32) {
      int u = (kk + kq) >> 3;
      short8 af[4], bfr[4];
#pragma unroll
      for (int i = 0; i < 4; ++i) {
        int row = wm + i * 16 + fr;
        af[i] = *(const short8*)&As[(row * 8 + (u ^ (row & 7))) * 8];
      }
#pragma unroll
      for (int j = 0; j < 4; ++j) {
        int row = wn + j * 16 + fr;
        bfr[j] = *(const short8*)&Bs[(row * 8 + (u ^ (row & 7))) * 8];
      }
#pragma unroll
      for (int i = 0; i < 4; ++i)
#pragma unroll
        for (int j = 0; j < 4; ++j)
          acc[i][j] = __builtin_amdgcn_mfma_f32_16x16x32_bf16(af[i], bfr[j], acc[i][j], 0, 0, 0);
    }
    __syncthreads();
  }
  const int fr = lane & 15;
  const int rg = (lane >> 4) * 4;
  unsigned short* Ew = &As[w * 1024];
  const int rr = lane >> 3;
  const int c8 = (lane & 7) * 8;
#pragma unroll
  for (int i = 0; i < 4; ++i) {
#pragma unroll
    for (int q = 0; q < 4; ++q)
#pragma unroll
      for (int j = 0; j < 4; ++j)
        Ew[(rg + q) * 64 + j * 16 + fr] = f2bf(acc[i][j][q]);
    ushort8v v0 = *(const ushort8v*)&Ew[rr * 64 + c8];
    ushort8v v1 = *(const ushort8v*)&Ew[(rr + 8) * 64 + c8];
    *(ushort8v*)(C + (size_t)(m0 + wm + i * 16 + rr) * ldc + n0 + wn + c8) = v0;
    *(ushort8v*)(C + (size_t)(m0 + wm + i * 16 + rr + 8) * ldc + n0 + wn + c8) = v1;
  }
}

// ---- BK=64, XOR-swizzled, 64(m)x128(n) tile, f32 out (out_proj) ----
__global__ __launch_bounds__(256) void gemm_m64_f32(
    const unsigned short* __restrict__ A, int lda,
    const unsigned short* __restrict__ B, int ldb,
    float* __restrict__ C, int ldc, int K) {
  __shared__ unsigned short As[64 * 64];
  __shared__ unsigned short Bs[128 * 64];
  const int tid = threadIdx.x;
  const int lane = tid & 63;
  const int w = tid >> 6;
  const int bid = blockIdx.x;
  const int xcd = bid & 7;
  const int q8  = bid >> 3;          // 0..63
  const int rsel = q8 >> 5;          // 0..1
  const int rp   = q8 & 31;          // 0..31
  const int reg  = xcd + 8 * rsel;   // 0..15
  const int m0 = ((reg >> 1) * 8 + (rp >> 2)) * 64;
  const int n0 = ((reg & 1) * 4 + (rp & 3)) * 128;
  const int wm = (w >> 1) * 32;
  const int wn = (w & 1) * 64;
  const int lrow = lane >> 3;
  const int lperm = lane & 7;
  floatx4 acc[2][4] = {};
  for (int k0 = 0; k0 < K; k0 += 64) {
#pragma unroll
    for (int j = 0; j < 6; ++j) {
      int g = j * 4 + w;                 // 0..23: 8 A-groups then 16 B-groups
      if (g < 8) {
        int row = g * 8 + lrow;
        int cg = (lperm ^ (row & 7)) * 8;
        gload_lds16(A + (size_t)(m0 + row) * lda + k0 + cg, &As[g * 512]);
      } else {
        int gb = g - 8;
        int row = gb * 8 + lrow;
        int cg = (lperm ^ (row & 7)) * 8;
        gload_lds16(B + (size_t)(n0 + row) * ldb + k0 + cg, &Bs[gb * 512]);
      }
    }
    __syncthreads();
    const int fr = lane & 15;
    const int kq = (lane >> 4) * 8;
#pragma unroll
    for (int kk = 0; kk < 64; kk += 32) {
      int u = (kk + kq) >> 3;
      short8 af[2], bfr[4];
#pragma unroll
      for (int i = 0; i < 2; ++i) {
        int row = wm + i * 16 + fr;
        af[i] = *(const short8*)&As[(row * 8 + (u ^ (row & 7))) * 8];
      }
#pragma unroll
      for (int j = 0; j < 4; ++j) {
        int row = wn + j * 16 + fr;
        bfr[j] = *(const short8*)&Bs[(row * 8 + (u ^ (row & 7))) * 8];
      }
#pragma unroll
      for (int i = 0; i < 2; ++i)
#pragma unroll
        for (int j = 0; j < 4; ++j)
          acc[i][j] = __builtin_amdgcn_mfma_f32_16x16x32_bf16(af[i], bfr[j], acc[i][j], 0, 0, 0);
    }
    __syncthreads();
  }
  const int col = lane & 15;
  const int rg = (lane >> 4) * 4;
#pragma unroll
  for (int i = 0; i < 2; ++i)
#pragma unroll
    for (int j = 0; j < 4; ++j)
#pragma unroll
      for (int r = 0; r < 4; ++r)
        C[(size_t)(m0 + wm + i * 16 + rg + r) * ldc + (n0 + wn + j * 16 + col)] = acc[i][j][r];
}

// ---------------- fused: dtscan (blocks 0..1023) + convs (blocks 1024..2175) ----------------
__global__ __launch_bounds__(256) void fused_dtconv_kernel(
    const float* __restrict__ DTraw, const float* __restrict__ dt_bias,
    const float* __restrict__ A_log, float* __restrict__ DTt, float* __restrict__ CUMS,
    const unsigned short* __restrict__ Zb, const float* __restrict__ wsp,
    const float* __restrict__ bsp, const float* __restrict__ wtp,
    const float* __restrict__ btp, unsigned short* __restrict__ XTb) {
  __shared__ __align__(16) char smem[32768];
  const int tid = threadIdx.x;
  if (blockIdx.x < 1024) {
    // ---- dtscan ----
    float* sc = (float*)smem;
    int idx = blockIdx.x * 256 + tid;
    int l  = idx & 2047;
    int rh = idx >> 11;
    int h  = rh & 31;
    int r  = rh >> 5;
    int bi = r & 1;
    int ls = (r < 2) ? l : flip_l(l);
    int ch = (r < 2) ? h : NHEADS + h;
    float raw = DTraw[((size_t)bi * SEQLEN + ls) * 64 + ch] + dt_bias[h];
    float dtv = (raw > 20.f) ? raw : log1pf(__expf(raw));
    DTt[idx] = dtv;
    float A = -__expf(A_log[h]);
    float run = dtv * A;
    sc[tid] = run;
    __syncthreads();
#pragma unroll
    for (int ofs = 1; ofs < 256; ofs <<= 1) {
      float add = (tid >= ofs) ? sc[tid - ofs] : 0.f;
      __syncthreads();
      run += add;
      sc[tid] = run;
      __syncthreads();
    }
    CUMS[idx] = run;
  } else {
    // ---- conv ----
    typedef float4 xsl_t[8][32];
    xsl_t* xsl = (xsl_t*)smem;     // [8][8][32] float4
    int bid = blockIdx.x - 1024;   // 0..1151
    const int bx = bid % 18;
    const int by = (bid / 18) & 31;
    const int bz = bid / 576;
    const int g  = tid & 31;
    const int fr = tid >> 5;
    const int c  = bx * 128 + g * 4;
    const int s0 = by * 8;
    const int bi = bz;
    float wsp_r[4][K_SP];
#pragma unroll
    for (int ch = 0; ch < 4; ++ch)
#pragma unroll
      for (int j = 0; j < K_SP; ++j) wsp_r[ch][j] = wsp[(c + ch) * K_SP + j];
    float4 bsp4 = *(const float4*)(bsp + c);
    float4 z[14];
#pragma unroll
    for (int i = 0; i < 14; ++i) {
      int ss = s0 - 3 + i;
      if (0 <= ss && ss < SPATIAL) {
        ushort4 v = *(const ushort4*)(Zb + ((size_t)bi * SEQLEN + (ss*8 + fr)) * ZLD + D_INNER + c);
        z[i] = make_float4(bf2f(v.x), bf2f(v.y), bf2f(v.z), bf2f(v.w));
      } else {
        z[i] = make_float4(0.f, 0.f, 0.f, 0.f);
      }
    }
#pragma unroll
    for (int so = 0; so < 8; ++so) {
      float4 a = bsp4;
#pragma unroll
      for (int j = 0; j < K_SP; ++j) {
        a.x += wsp_r[0][j] * z[so + j].x;
        a.y += wsp_r[1][j] * z[so + j].y;
        a.z += wsp_r[2][j] * z[so + j].z;
        a.w += wsp_r[3][j] * z[so + j].w;
      }
      a.x = silu_f(a.x); a.y = silu_f(a.y); a.z = silu_f(a.z); a.w = silu_f(a.w);
      xsl[fr][so][g] = a;
    }
    __syncthreads();
    float wtp_r[4][K_TP];
#pragma unroll
    for (int ch = 0; ch < 4; ++ch)
#pragma unroll
      for (int j = 0; j < K_TP; ++j) wtp_r[ch][j] = wtp[(c + ch) * K_TP + j];
    float4 btp4 = *(const float4*)(btp + c);
#pragma unroll
    for (int so = 0; so < 8; ++so) {
      float4 t = btp4;
#pragma unroll
      for (int j = 0; j < K_TP; ++j) {
        int ff = fr + j - (K_TP - 1);
        if (ff >= 0) {
          float4 xv = xsl[ff][so][g];
          t.x += wtp_r[0][j] * xv.x;
          t.y += wtp_r[1][j] * xv.y;
          t.z += wtp_r[2][j] * xv.z;
          t.w += wtp_r[3][j] * xv.w;
        }
      }
      ushort4 o;
      o.x = f2bf(silu_f(t.x)); o.y = f2bf(silu_f(t.y));
      o.z = f2bf(silu_f(t.z)); o.w = f2bf(silu_f(t.w));
      *(ushort4*)(XTb + ((size_t)bi * SEQLEN + ((s0 + so)*8 + fr)) * CONV_DIM + c) = o;
    }
  }
}

// ---------------- fused post-conv: chunk_state (0..511) + cb (512..831) + fcd-ts (832..1087) ----------------
__global__ __launch_bounds__(256) void fused_post_kernel(
    const unsigned short* __restrict__ XTb, const float* __restrict__ DTt,
    const float* __restrict__ CUMS, float* __restrict__ CBs,
    float* __restrict__ SCH, const unsigned short* __restrict__ FCDWb,
    float* __restrict__ FCD) {
  __shared__ __align__(16) char smem[35840];
  const int tid = threadIdx.x;
  const int bidx = blockIdx.x;
  const int lane = tid & 63;
  const int w = tid >> 6;
  if (bidx < 512) {
    // ---- chunk_state (c on XCD c via bidx&7) ----
    unsigned short* Xs = (unsigned short*)smem;         // 64*136
    unsigned short* Bsm = Xs + 64 * 136;                // 64*136
    float* gs = (float*)(Bsm + 64 * 136);               // 256
    int c = bidx & 7;
    int h = (bidx >> 3) & 31;
    int r = bidx >> 8;
    int bi = r;
    int rh = r * NHEADS + h;
    float cl = CUMS[(size_t)rh*SEQLEN + c*CHUNK + 255];
    gs[tid] = __expf(cl - CUMS[(size_t)rh*SEQLEN + c*CHUNK + tid]) * DTt[(size_t)rh*SEQLEN + c*CHUNK + tid];
    const int fr = lane & 15;
    const int kq = (lane >> 4) * 8;
    const int sr = tid >> 3;           // 0..31
    const int p0 = (tid & 7) * 8;      // 0..56
    const int swz = (tid & 7) << 3;
    floatx4 acc[4] = {};
    for (int half = 0; half < 2; ++half) {
      __syncthreads();                 // gs ready (half 0) / Xs,Bs reads done (half 1)
#pragma unroll
      for (int P = 0; P < 4; ++P) {
        int s = P * 32 + sr;           // 0..127 within half
        int l = c*CHUNK + half*128 + s;
        const unsigned short* row = XTb + ((size_t)bi*SEQLEN + l)*CONV_DIM;
        ushort8v xv = *(const ushort8v*)(row + h*HEADDIM + p0);
        ushort8v bv = *(const ushort8v*)(row + D_INNER + p0);
        float g = gs[half*128 + s];
        int cswz = s ^ swz;
#pragma unroll
        for (int q = 0; q < 8; ++q) {
          Xs[(p0 + q) * 136 + cswz] = f2bf(g * bf2f(xv[q]));
          Bsm[(p0 + q) * 136 + cswz] = bv[q];
        }
      }
      __syncthreads();
#pragma unroll
      for (int sl = 0; sl < 4; ++sl) {
        int s0 = sl * 32;
        int Ra = w*16 + fr;
        short8 af = *(const short8*)&Xs[Ra * 136 + ((s0 + kq) ^ (((Ra >> 3) & 7) << 3))];
#pragma unroll
        for (int j = 0; j < 4; ++j) {
          int Rb = j*16 + fr;
          short8 bf8 = *(const short8*)&Bsm[Rb * 136 + ((s0 + kq) ^ (((Rb >> 3) & 7) << 3))];
          acc[j] = __builtin_amdgcn_mfma_f32_16x16x32_bf16(af, bf8, acc[j], 0, 0, 0);
        }
      }
    }
    const int col = lane & 15;
    const int rg = (lane >> 4) * 4;
    size_t base = (((size_t)r*NCH + c)*NHEADS + h) * (size_t)(HEADDIM*D_STATE);
#pragma unroll
    for (int j = 0; j < 4; ++j)
#pragma unroll
      for (int q = 0; q < 4; ++q)
        SCH[base + (size_t)(w*16 + rg + q)*D_STATE + j*16 + col] = acc[j][q];
  } else if (bidx < 832) {
    // ---- cb: compacted lower-triangle tiles, XCD-aligned (c = idx&7 = bidx%8) ----
    const int TT0[10] = {0,1,1,2,2,2,3,3,3,3};
    const int SS0[10] = {0,0,1,0,1,2,0,1,2,3};
    int idx = bidx - 512;              // 0..319 ; (512+idx)%8 == idx%8
    int c = idx & 7;
    int k = idx >> 3;                  // 0..39
    int tt = k % 10;
    int r = k / 10;
    int t0 = TT0[tt] * 64;
    int s0 = SS0[tt] * 64;
    int bi = r & 1;
    int bOff = D_INNER + ((r < 2) ? 0 : 2*GN);
    int cOff = bOff + GN;
    const int fr = lane & 15;
    const int kq = (lane >> 4) * 8;
    int Lc = c * CHUNK + t0 + w * 16 + fr;
    if (r >= 2) Lc = flip_l(Lc);
    const unsigned short* crow = XTb + ((size_t)bi*SEQLEN + Lc)*CONV_DIM + cOff;
    short8 af0 = *(const short8*)(crow + kq);
    short8 af1 = *(const short8*)(crow + 32 + kq);
    floatx4 acc[4] = {};
#pragma unroll
    for (int j = 0; j < 4; ++j) {
      int Ls = c * CHUNK + s0 + j * 16 + fr;
      if (r >= 2) Ls = flip_l(Ls);
      const unsigned short* brow = XTb + ((size_t)bi*SEQLEN + Ls)*CONV_DIM + bOff;
      short8 bf0 = *(const short8*)(brow + kq);
      short8 bf1 = *(const short8*)(brow + 32 + kq);
      acc[j] = __builtin_amdgcn_mfma_f32_16x16x32_bf16(af0, bf0, acc[j], 0, 0, 0);
      acc[j] = __builtin_amdgcn_mfma_f32_16x16x32_bf16(af1, bf1, acc[j], 0, 0, 0);
    }
    const int col = lane & 15;
    const int rg = (lane >> 4) * 4;
    size_t base = (((size_t)r*NCH + c) * CHUNK) * CHUNK;
#pragma unroll
    for (int j = 0; j < 4; ++j)
#pragma unroll
      for (int q = 0; q < 4; ++q)
        CBs[base + (size_t)(t0 + w*16 + rg + q)*CHUNK + (s0 + j*16 + col)] = acc[j][q];
  } else {
    // ---- fcd tall-skinny GEMM: FCD[4096x32] = XTb[:, :2048] @ fc_D_w^T ----
    ts_body_bf16(XTb, CONV_DIM, FCDWb, 2048, FCD, 32, 32, 2048,
                 (bidx - 832) * 16, (float*)smem);
  }
}

// ---------------- Y = intra(triangular, MFMA) + inter (MFMA, fwd only, self-computed
// SPREV prefix from SCH — replaces the state_combine kernel), bf16 out ----------------
#define YS_ED(S0)                                                              \
  float edv[8];                                                                \
  { float4 e0_ = *(const float4*)&ecd[(S0) + kq];                              \
    float4 e1_ = *(const float4*)&ecd[(S0) + kq + 4];                          \
    edv[0]=e0_.x; edv[1]=e0_.y; edv[2]=e0_.z; edv[3]=e0_.w;                    \
    edv[4]=e1_.x; edv[5]=e1_.y; edv[6]=e1_.z; edv[7]=e1_.w; }

#define YS_BFR(S0)                                                             \
  short8 bfr[4];                                                               \
  _Pragma("unroll")                                                            \
  for (int j = 0; j < 4; ++j) {                                                \
    int R = j * 16 + fr;                                                       \
    bfr[j] = *(const short8*)&Xt[R * 264 + (((S0) + kq) ^ (((R >> 3) & 7) << 3))]; \
  }

#define YS_MFMA4(AF, ACCROW)                                                   \
  _Pragma("unroll")                                                            \
  for (int j = 0; j < 4; ++j)                                                  \
    ACCROW[j] = __builtin_amdgcn_mfma_f32_16x16x32_bf16(AF, bfr[j], ACCROW[j], 0, 0, 0);

#define YS_AF_NOMASK(C0, C1, E)                                                \
  { af_.u[0] = cvtpk_bf16(C0.x*(E)*edv[0], C0.y*(E)*edv[1]);                   \
    af_.u[1] = cvtpk_bf16(C0.z*(E)*edv[2], C0.w*(E)*edv[3]);                   \
    af_.u[2] = cvtpk_bf16(C1.x*(E)*edv[4], C1.y*(E)*edv[5]);                   \
    af_.u[3] = cvtpk_bf16(C1.z*(E)*edv[6], C1.w*(E)*edv[7]); }

#define YS_AF_MASK(C0, C1, E, TROW)                                            \
  { float wz[8] = {C0.x,C0.y,C0.z,C0.w,C1.x,C1.y,C1.z,C1.w};                   \
    _Pragma("unroll")                                                          \
    for (int jj = 0; jj < 8; ++jj) {                                           \
      float t_ = wz[jj]*(E)*edv[jj];                                           \
      wz[jj] = (kq + jj <= (TROW)) ? t_ : 0.f; }                               \
    af_.u[0]=cvtpk_bf16(wz[0],wz[1]); af_.u[1]=cvtpk_bf16(wz[2],wz[3]);        \
    af_.u[2]=cvtpk_bf16(wz[4],wz[5]); af_.u[3]=cvtpk_bf16(wz[6],wz[7]); }

#define YS_STRIP(KS, E2, ACC)                                                  \
  {                                                                            \
    const int t0s_ = (KS) * 32;                                                \
    const float* cbr0 = CBs + cbbase + (size_t)(t0s_ + fr) * CHUNK + kq;       \
    const float* cbr1 = cbr0 + (size_t)16 * CHUNK;                             \
    float4 a0 = *(const float4*)cbr0;                                          \
    float4 a1 = *(const float4*)(cbr0 + 4);                                    \
    float4 b0 = *(const float4*)cbr1;                                          \
    float4 b1 = *(const float4*)(cbr1 + 4);                                    \
    for (int sl = 0; sl < (KS); ++sl) {                                        \
      int s0 = sl * 32;                                                        \
      float4 na0 = *(const float4*)(cbr0 + s0 + 32);                           \
      float4 na1 = *(const float4*)(cbr0 + s0 + 36);                           \
      float4 nb0 = *(const float4*)(cbr1 + s0 + 32);                           \
      float4 nb1 = *(const float4*)(cbr1 + s0 + 36);                           \
      YS_ED(s0); YS_BFR(s0);                                                   \
      s8u af_;                                                                 \
      YS_AF_NOMASK(a0, a1, (E2)[0]);                                           \
      YS_MFMA4(af_.v, ACC[0]);                                                 \
      YS_AF_NOMASK(b0, b1, (E2)[1]);                                           \
      YS_MFMA4(af_.v, ACC[1]);                                                 \
      a0 = na0; a1 = na1; b0 = nb0; b1 = nb1;                                  \
    }                                                                          \
    {                                                                          \
      int s0 = (KS) * 32;                                                      \
      YS_ED(s0); YS_BFR(s0);                                                   \
      s8u af_;                                                                 \
      YS_AF_MASK(a0, a1, (E2)[0], fr);                                         \
      YS_MFMA4(af_.v, ACC[0]);                                                 \
      YS_AF_MASK(b0, b1, (E2)[1], 16 + fr);                                    \
      YS_MFMA4(af_.v, ACC[1]);                                                 \
    }                                                                          \
  }

#define YS_INTER(T0S, E2, ACC)                                                 \
  _Pragma("unroll")                                                            \
  for (int i = 0; i < 2; ++i) {                                                \
    int t = (T0S) + i * 16 + fr;                                               \
    const unsigned short* crow = XTb + ((size_t)bi*SEQLEN + c*CHUNK + t)*CONV_DIM + D_INNER + GN + n0 + kq; \
    ushort4 c0 = *(const ushort4*)crow;                                        \
    ushort4 c1 = *(const ushort4*)(crow + 4);                                  \
    float eI = (E2)[i];                                                        \
    s8u af_;                                                                   \
    af_.u[0] = cvtpk_bf16(bf2f(c0.x)*eI, bf2f(c0.y)*eI);                       \
    af_.u[1] = cvtpk_bf16(bf2f(c0.z)*eI, bf2f(c0.w)*eI);                       \
    af_.u[2] = cvtpk_bf16(bf2f(c1.x)*eI, bf2f(c1.y)*eI);                       \
    af_.u[3] = cvtpk_bf16(bf2f(c1.z)*eI, bf2f(c1.w)*eI);                       \
    YS_MFMA4(af_.v, ACC[i]);                                                   \
  }

#define YS_EPI(T0S, ACC)                                                       \
  _Pragma("unroll")                                                            \
  for (int i = 0; i < 2; ++i) {                                                \
    _Pragma("unroll")                                                          \
    for (int q = 0; q < 4; ++q)                                                \
      _Pragma("unroll")                                                        \
      for (int j = 0; j < 4; ++j)                                              \
        Ew[(rg + q) * 64 + j * 16 + fr] = f2bf(ACC[i][j][q]);                  \
    ushort8v v0 = *(const ushort8v*)&Ew[rr * 64 + c8];                         \
    ushort8v v1 = *(const ushort8v*)&Ew[(rr + 8) * 64 + c8];                   \
    *(ushort8v*)(Yb16 + ybase + (size_t)((T0S) + i*16 + rr) * D_INNER + c8) = v0;      \
    *(ushort8v*)(Yb16 + ybase + (size_t)((T0S) + i*16 + rr + 8) * D_INNER + c8) = v1;  \
  }

__global__ __launch_bounds__(256, 4) void yscan_kernel(const unsigned short* __restrict__ XTb,
                                                       const float* __restrict__ DTt,
                                                       const float* __restrict__ CUMS,
                                                       const float* __restrict__ CBs,
                                                       const float* __restrict__ SCH,
                                                       unsigned short* __restrict__ Yb16) {
  __shared__ unsigned short Xt[64 * 264];   // X^T, swizzled columns (33792 B)
  __shared__ float cums[CHUNK];
  __shared__ float ecd[CHUNK];              // exp(-cum[s]) * dt[s]
  int tid = threadIdx.x;
  int lane = tid & 63;
  int w = tid >> 6;
  // XCD-clustered decode: id = c + 8*h + 256*r
  int id = blockIdx.x;
  int c = id & 7;
  int h = (id >> 3) & 31;
  int r = id >> 8;
  int rh = r * NHEADS + h;
  int bi = r & 1;
  // ---- stage: full X^T tile + cums + ecd, one barrier ----
  {
    int sr = tid >> 3;                 // 0..31
    int p0 = (tid & 7) * 8;            // 0..56
    int swz = (tid & 7) << 3;          // col-swizzle for p-block (p>>3 const over q)
#pragma unroll
    for (int P = 0; P < 8; ++P) {
      int s = P * 32 + sr;
      int L = c * CHUNK + s;
      if (r >= 2) L = flip_l(L);
      ushort8v v = *(const ushort8v*)(XTb + ((size_t)bi * SEQLEN + L) * CONV_DIM + h * HEADDIM + p0);
      int cswz = s ^ swz;
#pragma unroll
      for (int q = 0; q < 8; ++q)
        Xt[(p0 + q) * 264 + cswz] = v[q];
    }
    float cv = CUMS[(size_t)rh * SEQLEN + c * CHUNK + tid];
    cums[tid] = cv;
    ecd[tid] = __expf(-cv) * DTt[(size_t)rh * SEQLEN + c * CHUNK + tid];
  }
  __syncthreads();
  const int fr = lane & 15;
  const int kq = (lane >> 4) * 8;
  // balanced strips: wave w owns 32-row t-strips kA=w and kB=7-w
  const int kA = w, kB = 7 - w;
  const int tA = kA * 32, tB = kB * 32;
  float eAr[2], eBr[2];
#pragma unroll
  for (int i = 0; i < 2; ++i) {
    eAr[i] = __expf(cums[tA + i * 16 + fr]);
    eBr[i] = __expf(cums[tB + i * 16 + fr]);
  }
  floatx4 accA[2][4] = {};
  floatx4 accB[2][4] = {};
  size_t cbbase = (((size_t)r * NCH + c) * CHUNK) * CHUNK;
  // ---- inter FIRST (register pressure: sp dies before intra) ----
  if (r < 2) {
#pragma unroll
    for (int ns = 0; ns < 2; ++ns) {
      int n0 = ns * 32;
      // self-computed SPREV slice: S = dec(c')*S + v(c') for c' = 0..c-1
      float sp[4][8] = {};
      for (int cp = 0; cp < c; ++cp) {
        float dec = __expf(CUMS[(size_t)rh*SEQLEN + cp*CHUNK + 255]);
        const float* sb = SCH + (((size_t)r*NCH + cp)*NHEADS + h) * (size_t)(HEADDIM*D_STATE);
#pragma unroll
        for (int j = 0; j < 4; ++j) {
          const float* p = sb + (size_t)(j*16 + fr)*D_STATE + n0 + kq;
          float4 v0 = *(const float4*)p;
          float4 v1 = *(const float4*)(p + 4);
          sp[j][0] = dec*sp[j][0] + v0.x; sp[j][1] = dec*sp[j][1] + v0.y;
          sp[j][2] = dec*sp[j][2] + v0.z; sp[j][3] = dec*sp[j][3] + v0.w;
          sp[j][4] = dec*sp[j][4] + v1.x; sp[j][5] = dec*sp[j][5] + v1.y;
          sp[j][6] = dec*sp[j][6] + v1.z; sp[j][7] = dec*sp[j][7] + v1.w;
        }
      }
      short8 bfr[4];
#pragma unroll
      for (int j = 0; j < 4; ++j) {
        s8u bb;
        bb.u[0] = cvtpk_bf16(sp[j][0], sp[j][1]);
        bb.u[1] = cvtpk_bf16(sp[j][2], sp[j][3]);
        bb.u[2] = cvtpk_bf16(sp[j][4], sp[j][5]);
        bb.u[3] = cvtpk_bf16(sp[j][6], sp[j][7]);
        bfr[j] = bb.v;
      }
      YS_INTER(tA, eAr, accA);
      YS_INTER(tB, eBr, accB);
    }
  }
  // ---- intra strips ----
  YS_STRIP(kA, eAr, accA);
  YS_STRIP(kB, eBr, accB);
  // bf16 epilogue: per-wave LDS transpose scratch inside Xt (barrier: Xt reads done)
  __syncthreads();
  unsigned short* Ew = Xt + w * 1024;
  const int rg = (lane >> 4) * 4;
  const int rr = lane >> 3;
  const int c8 = (lane & 7) * 8;
  size_t ybase = ((size_t)r*SEQLEN + c*CHUNK)*D_INNER + h*HEADDIM;
  YS_EPI(tA, accA);
  YS_EPI(tB, accB);
}

// ---------------- shifts + x_res + RMSNorm + gate (vectorized, -> bf16) ----------------
__global__ __launch_bounds__(256) void combine_kernel(const unsigned short* __restrict__ Y,
                                                      const unsigned short* __restrict__ XTb,
                                                      const float* __restrict__ FCD,
                                                      const float* __restrict__ Dp,
                                                      const unsigned short* __restrict__ Zb,
                                                      const float* __restrict__ norm_w,
                                                      unsigned short* __restrict__ YPb) {
  __shared__ float red4[4];
  int row = blockIdx.x;
  int bi = row >> 11;
  int l = row & 2047;
  int s = l >> 3, fr = l & 7;
  int tid = threadIdx.x;
  int d0 = tid * 8;
  const unsigned short* yf = (l >= 1) ? Y + ((size_t)bi*SEQLEN + (l-1))*D_INNER + d0 : nullptr;
  const unsigned short* yr = (s >= 1) ? Y + ((size_t)(2+bi)*SEQLEN + ((s-1)*8 + (7-fr)))*D_INNER + d0 : nullptr;
  const unsigned short* xr = XTb + ((size_t)row)*CONV_DIM + d0;
  float fcv = FCD[(size_t)row*NHEADS + (d0 >> 6)] + Dp[d0 >> 6];
  ushort8v xv8 = *(const ushort8v*)xr;
  float v[8];
#pragma unroll
  for (int q = 0; q < 8; ++q) v[q] = bf2f(xv8[q]) * fcv;
  if (yf) {
    ushort8v a = *(const ushort8v*)yf;
#pragma unroll
    for (int q = 0; q < 8; ++q) v[q] += bf2f(a[q]);
  }
  if (yr) {
    ushort8v a = *(const ushort8v*)yr;
#pragma unroll
    for (int q = 0; q < 8; ++q) v[q] += bf2f(a[q]);
  }
  float ss = 0.f;
#pragma unroll
  for (int q = 0; q < 8; ++q) ss += v[q] * v[q];
#pragma unroll
  for (int d = 1; d < 64; d <<= 1) ss += __shfl_xor(ss, d, 64);
  if ((tid & 63) == 0) red4[tid >> 6] = ss;
  __syncthreads();
  float tot = red4[0] + red4[1] + red4[2] + red4[3];
  float rs = rsqrtf(tot / (float)D_INNER + 1e-5f);
  ushort8v zv8 = *(const ushort8v*)(Zb + ((size_t)row)*ZLD + d0);
  float4 nw0 = *(const float4*)(norm_w + d0);
  float4 nw1 = *(const float4*)(norm_w + d0 + 4);
  float nw[8] = {nw0.x,nw0.y,nw0.z,nw0.w,nw1.x,nw1.y,nw1.z,nw1.w};
  ushort8v o;
#pragma unroll
  for (int q = 0; q < 8; ++q)
    o[q] = f2bf(v[q] * rs * nw[q] * silu_f(bf2f(zv8[q])));
  *(ushort8v*)(YPb + (size_t)row*D_INNER + d0) = o;
}

extern "C" void kernel_launch(void* const* d_in, const int* in_sizes, int n_in,
                              void* d_out, int out_size, void* d_ws, size_t ws_size,
                              hipStream_t stream) {
  (void)in_sizes; (void)n_in; (void)out_size; (void)ws_size;
  const float* u          = (const float*)d_in[0];
  const float* in_proj_w  = (const float*)d_in[1];
  const float* conv_sp_w  = (const float*)d_in[2];
  const float* conv_sp_b  = (const float*)d_in[3];
  const float* conv_tp_w  = (const float*)d_in[4];
  const float* conv_tp_b  = (const float*)d_in[5];
  const float* dt_bias    = (const float*)d_in[6];
  const float* A_log      = (const float*)d_in[7];
  const float* Dp         = (const float*)d_in[8];
  const float* fc_D_w     = (const float*)d_in[9];
  const float* norm_w     = (const float*)d_in[10];
  const float* out_proj_w = (const float*)d_in[11];
  float* out = (float*)d_out;
  float* ws = (float*)d_ws;

  // workspace layout (f32-element offsets; Z/XT/Y regions hold bf16)
  float* Z     = ws;                       // 17,825,792 slots (bf16 uses half)
  float* SH    = Z     + 17825792ULL;      // 9,437,184  (CBs -> YPb)
  float* XT    = SH    + 9437184ULL;       // 9,437,184  (bf16 uses half)
  float* DTt   = XT    + 9437184ULL;       // 262,144
  float* Yb    = DTt   + 262144ULL;        // 16,777,216 (bf16 Y in first half; SCH; Wob/FCDWb tail)
  float* SPREV = Yb    + 16777216ULL;      // 2,097,152 (unused; layout kept)
  float* FCD   = SPREV + 2097152ULL;       // 131,072
  float* DTraw = FCD   + 131072ULL;        // 262,144
  float* CUMS  = DTraw + 262144ULL;        // 262,144

  unsigned short* Zb   = (unsigned short*)Z;
  unsigned short* XTb  = (unsigned short*)XT;
  unsigned short* Yb16 = (unsigned short*)Yb;            // floats [0, 8,388,608)
  unsigned short* Ub   = (unsigned short*)Yb;            // staging (dead before yscan)
  unsigned short* Wb   = (unsigned short*)Yb + 4194304ULL;   // 4416x1024 ushorts (incl. dt rows)
  float* SCH = Yb + 8388608ULL;                          // floats [8,388,608, 10,485,760)
  unsigned short* Wob = (unsigned short*)(Yb + 10485760ULL); // out_proj bf16, 1024x2048
  unsigned short* FCDWb = (unsigned short*)(Yb + 11534336ULL); // fc_D_w bf16, 32x2048
  unsigned short* YPb = (unsigned short*)SH;

  cast4_bf16_kernel<<<10624, 256, 0, stream>>>(u, Ub, 4096, in_proj_w, Wb, 4416,
                                               out_proj_w, Wob, 2048, fc_D_w, FCDWb);
  gemm_main_kernel<<<dim3(1344), 256, 0, stream>>>(Ub, 1024, Wb, 1024, Zb, ZLD, 1024,
                                                   Wb + 4352ULL*1024, DTraw);
  fused_dtconv_kernel<<<2176, 256, 0, stream>>>(DTraw, dt_bias, A_log, DTt, CUMS,
                                                Zb, conv_sp_w, conv_sp_b,
                                                conv_tp_w, conv_tp_b, XTb);
  fused_post_kernel<<<1088, 256, 0, stream>>>(XTb, DTt, CUMS, SH, SCH, FCDWb, FCD);
  yscan_kernel<<<dim3(1024), 256, 0, stream>>>(XTb, DTt, CUMS, SH, SCH, Yb16);
  combine_kernel<<<4096, 256, 0, stream>>>(Yb16, XTb, FCD, Dp, Zb, norm_w, YPb);
  gemm_m64_f32<<<dim3(512), 256, 0, stream>>>(YPb, 2048, Wob, 2048, out, 1024, 2048);
}

// Round 7
// 273.274 us; speedup vs baseline: 1.1063x; 1.1063x over previous
//
#include <hip/hip_runtime.h>
#include <hip/hip_bf16.h>
#include <math.h>

#define D_STATE   64
#define HEADDIM   64
#define D_INNER   2048
#define NHEADS    32
#define GN        64
#define CONV_DIM  2304
#define D_IN_PROJ 4416
#define ZLD       4352      /* z + xBC columns only (dt handled separately) */
#define K_SP      7
#define K_TP      4
#define CHUNK     256
#define BATCHN    2
#define FRAMES    8
#define SPATIAL   256
#define SEQLEN    2048
#define NCH       8
#define MTOT      4096

typedef __attribute__((ext_vector_type(8))) short short8;
typedef __attribute__((ext_vector_type(8))) unsigned short ushort8v;
typedef __attribute__((ext_vector_type(4))) float floatx4;

__device__ __forceinline__ float silu_f(float x) { return x / (1.f + __expf(-x)); }
__device__ __forceinline__ int flip_l(int l) { return (l & ~7) | (7 - (l & 7)); }
__device__ __forceinline__ unsigned short f2bf(float f) {
  unsigned int u = __float_as_uint(f);
  unsigned int r = (u + 0x7fffu + ((u >> 16) & 1u)) >> 16;
  return (unsigned short)r;
}
__device__ __forceinline__ float bf2f(unsigned short s) {
  return __uint_as_float(((unsigned int)s) << 16);
}
__device__ __forceinline__ unsigned int cvtpk_bf16(float lo, float hi) {
  unsigned int r;
  asm("v_cvt_pk_bf16_f32 %0, %1, %2" : "=v"(r) : "v"(lo), "v"(hi));
  return r;
}
typedef union { short8 v; unsigned int u[4]; } s8u;
__device__ __forceinline__ void gload_lds16(const unsigned short* g, unsigned short* l) {
  __builtin_amdgcn_global_load_lds((const __attribute__((address_space(1))) void*)g,
                                   (__attribute__((address_space(3))) void*)l, 16, 0, 0);
}

// ---------------- f32 -> bf16 cast (four tensors, one launch) ----------------
__global__ __launch_bounds__(256) void cast4_bf16_kernel(const float* __restrict__ a,
                                                         unsigned short* __restrict__ oa,
                                                         int na,
                                                         const float* __restrict__ b,
                                                         unsigned short* __restrict__ ob,
                                                         int nb,
                                                         const float* __restrict__ c,
                                                         unsigned short* __restrict__ oc,
                                                         int nc,
                                                         const float* __restrict__ d,
                                                         unsigned short* __restrict__ od) {
  int bid = blockIdx.x;
  const float* in;
  unsigned short* out;
  size_t blk;
  if (bid < na)                 { in = a; out = oa; blk = bid; }
  else if (bid < na + nb)       { in = b; out = ob; blk = bid - na; }
  else if (bid < na + nb + nc)  { in = c; out = oc; blk = bid - na - nb; }
  else                          { in = d; out = od; blk = bid - na - nb - nc; }
  size_t i = (blk * 256 + threadIdx.x) * 4;
  float4 v = *(const float4*)(in + i);
  ushort4 o;
  o.x = f2bf(v.x); o.y = f2bf(v.y); o.z = f2bf(v.z); o.w = f2bf(v.w);
  *(ushort4*)(out + i) = o;
}

// ---------------- tall-skinny MFMA GEMM body: C[M x N] = A(bf16) @ B(bf16)^T ----------------
__device__ __forceinline__ void ts_body_bf16(const unsigned short* __restrict__ A, int lda,
                                             const unsigned short* __restrict__ B, int ldb,
                                             float* __restrict__ C, int ldc, int N, int K,
                                             int m0, float* red) {
  const int tid = threadIdx.x;
  const int lane = tid & 63;
  const int w = tid >> 6;
  const int fr = lane & 15;
  const int kq = (lane >> 4) * 8;
  const int nt = N >> 4;
  const int kseg = K >> 2;
  const int k0 = w * kseg;
  floatx4 acc[4] = {};
  for (int k = k0; k < k0 + kseg; k += 32) {
    short8 af = *(const short8*)(A + (size_t)(m0 + fr) * lda + k + kq);
    for (int j = 0; j < nt; ++j) {
      short8 bf8 = *(const short8*)(B + (size_t)(j * 16 + fr) * ldb + k + kq);
      acc[j] = __builtin_amdgcn_mfma_f32_16x16x32_bf16(af, bf8, acc[j], 0, 0, 0);
    }
  }
  const int rg = (lane >> 4) * 4;
  for (int j = 0; j < nt; ++j)
#pragma unroll
    for (int q = 0; q < 4; ++q)
      red[w * 1024 + j * 256 + (rg + q) * 16 + fr] = acc[j][q];
  __syncthreads();
  const int entries = nt * 256;
  for (int e = tid; e < entries; e += 256) {
    float s = red[e] + red[1024 + e] + red[2048 + e] + red[3072 + e];
    int j = e >> 8, idx = e & 255, row = idx >> 4, col = idx & 15;
    C[(size_t)(m0 + row) * ldc + j * 16 + col] = s;
  }
}

// ---- merged: in_proj GEMM (blocks 0..1087, 128x128, XCD-region swizzle) +
//      dt tall-skinny GEMM (blocks 1088..1343) ----
__global__ __launch_bounds__(256) void gemm_main_kernel(
    const unsigned short* __restrict__ A, int lda,
    const unsigned short* __restrict__ B, int ldb,
    unsigned short* __restrict__ C, int ldc, int K,
    const unsigned short* __restrict__ Bdt, float* __restrict__ DTraw) {
  __shared__ __align__(16) char smem[32768];
  const int tid = threadIdx.x;
  const int lane = tid & 63;
  const int w = tid >> 6;
  if (blockIdx.x >= 1088) {
    ts_body_bf16(A, lda, Bdt, lda, DTraw, 64, 64, K,
                 (blockIdx.x - 1088) * 16, (float*)smem);
    return;
  }
  unsigned short* As = (unsigned short*)smem;     // 128*64
  unsigned short* Bs = As + 128 * 64;             // 128*64
  const int bid = blockIdx.x;
  const int xcd = bid & 7;
  const int rp  = bid >> 3;          // 0..135
  const int px  = rp % 17;
  const int py  = rp / 17;           // 0..7
  const int m0 = ((xcd >> 1) * 8 + py) * 128;
  const int n0 = ((xcd & 1) * 17 + px) * 128;
  const int wm = (w >> 1) * 64;
  const int wn = (w & 1) * 64;
  const int lrow = lane >> 3;            // 0..7 within 8-row group
  const int lperm = lane & 7;            // LDS slot within row
  floatx4 acc[4][4] = {};
  for (int k0 = 0; k0 < K; k0 += 64) {
#pragma unroll
    for (int j = 0; j < 8; ++j) {
      int g = j * 4 + w;                 // 0..31: 16 A-groups then 16 B-groups
      if (g < 16) {
        int row = g * 8 + lrow;
        int cg = (lperm ^ (row & 7)) * 8;
        gload_lds16(A + (size_t)(m0 + row) * lda + k0 + cg, &As[g * 512]);
      } else {
        int gb = g - 16;
        int row = gb * 8 + lrow;
        int cg = (lperm ^ (row & 7)) * 8;
        gload_lds16(B + (size_t)(n0 + row) * ldb + k0 + cg, &Bs[gb * 512]);
      }
    }
    __syncthreads();
    const int fr = lane & 15;
    const int kq = (lane >> 4) * 8;
#pragma unroll
    for (int kk = 0; kk < 64; kk += 32) {
      int u = (kk + kq) >> 3;
      short8 af[4], bfr[4];
#pragma unroll
      for (int i = 0; i < 4; ++i) {
        int row = wm + i * 16 + fr;
        af[i] = *(const short8*)&As[(row * 8 + (u ^ (row & 7))) * 8];
      }
#pragma unroll
      for (int j = 0; j < 4; ++j) {
        int row = wn + j * 16 + fr;
        bfr[j] = *(const short8*)&Bs[(row * 8 + (u ^ (row & 7))) * 8];
      }
#pragma unroll
      for (int i = 0; i < 4; ++i)
#pragma unroll
        for (int j = 0; j < 4; ++j)
          acc[i][j] = __builtin_amdgcn_mfma_f32_16x16x32_bf16(af[i], bfr[j], acc[i][j], 0, 0, 0);
    }
    __syncthreads();
  }
  const int fr = lane & 15;
  const int rg = (lane >> 4) * 4;
  unsigned short* Ew = &As[w * 1024];
  const int rr = lane >> 3;
  const int c8 = (lane & 7) * 8;
#pragma unroll
  for (int i = 0; i < 4; ++i) {
#pragma unroll
    for (int q = 0; q < 4; ++q)
#pragma unroll
      for (int j = 0; j < 4; ++j)
        Ew[(rg + q) * 64 + j * 16 + fr] = f2bf(acc[i][j][q]);
    ushort8v v0 = *(const ushort8v*)&Ew[rr * 64 + c8];
    ushort8v v1 = *(const ushort8v*)&Ew[(rr + 8) * 64 + c8];
    *(ushort8v*)(C + (size_t)(m0 + wm + i * 16 + rr) * ldc + n0 + wn + c8) = v0;
    *(ushort8v*)(C + (size_t)(m0 + wm + i * 16 + rr + 8) * ldc + n0 + wn + c8) = v1;
  }
}

// ---- BK=64, XOR-swizzled, 64(m)x128(n) tile, f32 out (out_proj) ----
__global__ __launch_bounds__(256) void gemm_m64_f32(
    const unsigned short* __restrict__ A, int lda,
    const unsigned short* __restrict__ B, int ldb,
    float* __restrict__ C, int ldc, int K) {
  __shared__ unsigned short As[64 * 64];
  __shared__ unsigned short Bs[128 * 64];
  const int tid = threadIdx.x;
  const int lane = tid & 63;
  const int w = tid >> 6;
  const int bid = blockIdx.x;
  const int xcd = bid & 7;
  const int q8  = bid >> 3;          // 0..63
  const int rsel = q8 >> 5;          // 0..1
  const int rp   = q8 & 31;          // 0..31
  const int reg  = xcd + 8 * rsel;   // 0..15
  const int m0 = ((reg >> 1) * 8 + (rp >> 2)) * 64;
  const int n0 = ((reg & 1) * 4 + (rp & 3)) * 128;
  const int wm = (w >> 1) * 32;
  const int wn = (w & 1) * 64;
  const int lrow = lane >> 3;
  const int lperm = lane & 7;
  floatx4 acc[2][4] = {};
  for (int k0 = 0; k0 < K; k0 += 64) {
#pragma unroll
    for (int j = 0; j < 6; ++j) {
      int g = j * 4 + w;                 // 0..23: 8 A-groups then 16 B-groups
      if (g < 8) {
        int row = g * 8 + lrow;
        int cg = (lperm ^ (row & 7)) * 8;
        gload_lds16(A + (size_t)(m0 + row) * lda + k0 + cg, &As[g * 512]);
      } else {
        int gb = g - 8;
        int row = gb * 8 + lrow;
        int cg = (lperm ^ (row & 7)) * 8;
        gload_lds16(B + (size_t)(n0 + row) * ldb + k0 + cg, &Bs[gb * 512]);
      }
    }
    __syncthreads();
    const int fr = lane & 15;
    const int kq = (lane >> 4) * 8;
#pragma unroll
    for (int kk = 0; kk < 64; kk += 32) {
      int u = (kk + kq) >> 3;
      short8 af[2], bfr[4];
#pragma unroll
      for (int i = 0; i < 2; ++i) {
        int row = wm + i * 16 + fr;
        af[i] = *(const short8*)&As[(row * 8 + (u ^ (row & 7))) * 8];
      }
#pragma unroll
      for (int j = 0; j < 4; ++j) {
        int row = wn + j * 16 + fr;
        bfr[j] = *(const short8*)&Bs[(row * 8 + (u ^ (row & 7))) * 8];
      }
#pragma unroll
      for (int i = 0; i < 2; ++i)
#pragma unroll
        for (int j = 0; j < 4; ++j)
          acc[i][j] = __builtin_amdgcn_mfma_f32_16x16x32_bf16(af[i], bfr[j], acc[i][j], 0, 0, 0);
    }
    __syncthreads();
  }
  const int col = lane & 15;
  const int rg = (lane >> 4) * 4;
#pragma unroll
  for (int i = 0; i < 2; ++i)
#pragma unroll
    for (int j = 0; j < 4; ++j)
#pragma unroll
      for (int r = 0; r < 4; ++r)
        C[(size_t)(m0 + wm + i * 16 + rg + r) * ldc + (n0 + wn + j * 16 + col)] = acc[i][j][r];
}

// ---------------- fused: dtscan (blocks 0..1023) + convs (blocks 1024..2175) ----------------
__global__ __launch_bounds__(256) void fused_dtconv_kernel(
    const float* __restrict__ DTraw, const float* __restrict__ dt_bias,
    const float* __restrict__ A_log, float* __restrict__ DTt, float* __restrict__ CUMS,
    const unsigned short* __restrict__ Zb, const float* __restrict__ wsp,
    const float* __restrict__ bsp, const float* __restrict__ wtp,
    const float* __restrict__ btp, unsigned short* __restrict__ XTb) {
  __shared__ __align__(16) char smem[32768];
  const int tid = threadIdx.x;
  if (blockIdx.x < 1024) {
    // ---- dtscan ----
    float* sc = (float*)smem;
    int idx = blockIdx.x * 256 + tid;
    int l  = idx & 2047;
    int rh = idx >> 11;
    int h  = rh & 31;
    int r  = rh >> 5;
    int bi = r & 1;
    int ls = (r < 2) ? l : flip_l(l);
    int ch = (r < 2) ? h : NHEADS + h;
    float raw = DTraw[((size_t)bi * SEQLEN + ls) * 64 + ch] + dt_bias[h];
    float dtv = (raw > 20.f) ? raw : log1pf(__expf(raw));
    DTt[idx] = dtv;
    float A = -__expf(A_log[h]);
    float run = dtv * A;
    sc[tid] = run;
    __syncthreads();
#pragma unroll
    for (int ofs = 1; ofs < 256; ofs <<= 1) {
      float add = (tid >= ofs) ? sc[tid - ofs] : 0.f;
      __syncthreads();
      run += add;
      sc[tid] = run;
      __syncthreads();
    }
    CUMS[idx] = run;
  } else {
    // ---- conv ----
    typedef float4 xsl_t[8][32];
    xsl_t* xsl = (xsl_t*)smem;     // [8][8][32] float4
    int bid = blockIdx.x - 1024;   // 0..1151
    const int bx = bid % 18;
    const int by = (bid / 18) & 31;
    const int bz = bid / 576;
    const int g  = tid & 31;
    const int fr = tid >> 5;
    const int c  = bx * 128 + g * 4;
    const int s0 = by * 8;
    const int bi = bz;
    float wsp_r[4][K_SP];
#pragma unroll
    for (int ch = 0; ch < 4; ++ch)
#pragma unroll
      for (int j = 0; j < K_SP; ++j) wsp_r[ch][j] = wsp[(c + ch) * K_SP + j];
    float4 bsp4 = *(const float4*)(bsp + c);
    float4 z[14];
#pragma unroll
    for (int i = 0; i < 14; ++i) {
      int ss = s0 - 3 + i;
      if (0 <= ss && ss < SPATIAL) {
        ushort4 v = *(const ushort4*)(Zb + ((size_t)bi * SEQLEN + (ss*8 + fr)) * ZLD + D_INNER + c);
        z[i] = make_float4(bf2f(v.x), bf2f(v.y), bf2f(v.z), bf2f(v.w));
      } else {
        z[i] = make_float4(0.f, 0.f, 0.f, 0.f);
      }
    }
#pragma unroll
    for (int so = 0; so < 8; ++so) {
      float4 a = bsp4;
#pragma unroll
      for (int j = 0; j < K_SP; ++j) {
        a.x += wsp_r[0][j] * z[so + j].x;
        a.y += wsp_r[1][j] * z[so + j].y;
        a.z += wsp_r[2][j] * z[so + j].z;
        a.w += wsp_r[3][j] * z[so + j].w;
      }
      a.x = silu_f(a.x); a.y = silu_f(a.y); a.z = silu_f(a.z); a.w = silu_f(a.w);
      xsl[fr][so][g] = a;
    }
    __syncthreads();
    float wtp_r[4][K_TP];
#pragma unroll
    for (int ch = 0; ch < 4; ++ch)
#pragma unroll
      for (int j = 0; j < K_TP; ++j) wtp_r[ch][j] = wtp[(c + ch) * K_TP + j];
    float4 btp4 = *(const float4*)(btp + c);
#pragma unroll
    for (int so = 0; so < 8; ++so) {
      float4 t = btp4;
#pragma unroll
      for (int j = 0; j < K_TP; ++j) {
        int ff = fr + j - (K_TP - 1);
        if (ff >= 0) {
          float4 xv = xsl[ff][so][g];
          t.x += wtp_r[0][j] * xv.x;
          t.y += wtp_r[1][j] * xv.y;
          t.z += wtp_r[2][j] * xv.z;
          t.w += wtp_r[3][j] * xv.w;
        }
      }
      ushort4 o;
      o.x = f2bf(silu_f(t.x)); o.y = f2bf(silu_f(t.y));
      o.z = f2bf(silu_f(t.z)); o.w = f2bf(silu_f(t.w));
      *(ushort4*)(XTb + ((size_t)bi * SEQLEN + ((s0 + so)*8 + fr)) * CONV_DIM + c) = o;
    }
  }
}

// ---------------- fused post-conv: chunk_state (0..511) + cb (512..831) + fcd-ts (832..1087) ----------------
__global__ __launch_bounds__(256) void fused_post_kernel(
    const unsigned short* __restrict__ XTb, const float* __restrict__ DTt,
    const float* __restrict__ CUMS, float* __restrict__ CBs,
    float* __restrict__ SCH, const unsigned short* __restrict__ FCDWb,
    float* __restrict__ FCD) {
  __shared__ __align__(16) char smem[35840];
  const int tid = threadIdx.x;
  const int bidx = blockIdx.x;
  const int lane = tid & 63;
  const int w = tid >> 6;
  if (bidx < 512) {
    // ---- chunk_state (c on XCD c via bidx&7) ----
    unsigned short* Xs = (unsigned short*)smem;         // 64*136
    unsigned short* Bsm = Xs + 64 * 136;                // 64*136
    float* gs = (float*)(Bsm + 64 * 136);               // 256
    int c = bidx & 7;
    int h = (bidx >> 3) & 31;
    int r = bidx >> 8;
    int bi = r;
    int rh = r * NHEADS + h;
    float cl = CUMS[(size_t)rh*SEQLEN + c*CHUNK + 255];
    gs[tid] = __expf(cl - CUMS[(size_t)rh*SEQLEN + c*CHUNK + tid]) * DTt[(size_t)rh*SEQLEN + c*CHUNK + tid];
    const int fr = lane & 15;
    const int kq = (lane >> 4) * 8;
    const int sr = tid >> 3;           // 0..31
    const int p0 = (tid & 7) * 8;      // 0..56
    const int swz = (tid & 7) << 3;
    floatx4 acc[4] = {};
    for (int half = 0; half < 2; ++half) {
      __syncthreads();                 // gs ready (half 0) / Xs,Bs reads done (half 1)
#pragma unroll
      for (int P = 0; P < 4; ++P) {
        int s = P * 32 + sr;           // 0..127 within half
        int l = c*CHUNK + half*128 + s;
        const unsigned short* row = XTb + ((size_t)bi*SEQLEN + l)*CONV_DIM;
        ushort8v xv = *(const ushort8v*)(row + h*HEADDIM + p0);
        ushort8v bv = *(const ushort8v*)(row + D_INNER + p0);
        float g = gs[half*128 + s];
        int cswz = s ^ swz;
#pragma unroll
        for (int q = 0; q < 8; ++q) {
          Xs[(p0 + q) * 136 + cswz] = f2bf(g * bf2f(xv[q]));
          Bsm[(p0 + q) * 136 + cswz] = bv[q];
        }
      }
      __syncthreads();
#pragma unroll
      for (int sl = 0; sl < 4; ++sl) {
        int s0 = sl * 32;
        int Ra = w*16 + fr;
        short8 af = *(const short8*)&Xs[Ra * 136 + ((s0 + kq) ^ (((Ra >> 3) & 7) << 3))];
#pragma unroll
        for (int j = 0; j < 4; ++j) {
          int Rb = j*16 + fr;
          short8 bf8 = *(const short8*)&Bsm[Rb * 136 + ((s0 + kq) ^ (((Rb >> 3) & 7) << 3))];
          acc[j] = __builtin_amdgcn_mfma_f32_16x16x32_bf16(af, bf8, acc[j], 0, 0, 0);
        }
      }
    }
    const int col = lane & 15;
    const int rg = (lane >> 4) * 4;
    size_t base = (((size_t)r*NCH + c)*NHEADS + h) * (size_t)(HEADDIM*D_STATE);
#pragma unroll
    for (int j = 0; j < 4; ++j)
#pragma unroll
      for (int q = 0; q < 4; ++q)
        SCH[base + (size_t)(w*16 + rg + q)*D_STATE + j*16 + col] = acc[j][q];
  } else if (bidx < 832) {
    // ---- cb: compacted lower-triangle tiles, XCD-aligned (c = idx&7 = bidx%8) ----
    const int TT0[10] = {0,1,1,2,2,2,3,3,3,3};
    const int SS0[10] = {0,0,1,0,1,2,0,1,2,3};
    int idx = bidx - 512;              // 0..319 ; (512+idx)%8 == idx%8
    int c = idx & 7;
    int k = idx >> 3;                  // 0..39
    int tt = k % 10;
    int r = k / 10;
    int t0 = TT0[tt] * 64;
    int s0 = SS0[tt] * 64;
    int bi = r & 1;
    int bOff = D_INNER + ((r < 2) ? 0 : 2*GN);
    int cOff = bOff + GN;
    const int fr = lane & 15;
    const int kq = (lane >> 4) * 8;
    int Lc = c * CHUNK + t0 + w * 16 + fr;
    if (r >= 2) Lc = flip_l(Lc);
    const unsigned short* crow = XTb + ((size_t)bi*SEQLEN + Lc)*CONV_DIM + cOff;
    short8 af0 = *(const short8*)(crow + kq);
    short8 af1 = *(const short8*)(crow + 32 + kq);
    floatx4 acc[4] = {};
#pragma unroll
    for (int j = 0; j < 4; ++j) {
      int Ls = c * CHUNK + s0 + j * 16 + fr;
      if (r >= 2) Ls = flip_l(Ls);
      const unsigned short* brow = XTb + ((size_t)bi*SEQLEN + Ls)*CONV_DIM + bOff;
      short8 bf0 = *(const short8*)(brow + kq);
      short8 bf1 = *(const short8*)(brow + 32 + kq);
      acc[j] = __builtin_amdgcn_mfma_f32_16x16x32_bf16(af0, bf0, acc[j], 0, 0, 0);
      acc[j] = __builtin_amdgcn_mfma_f32_16x16x32_bf16(af1, bf1, acc[j], 0, 0, 0);
    }
    const int col = lane & 15;
    const int rg = (lane >> 4) * 4;
    size_t base = (((size_t)r*NCH + c) * CHUNK) * CHUNK;
#pragma unroll
    for (int j = 0; j < 4; ++j)
#pragma unroll
      for (int q = 0; q < 4; ++q)
        CBs[base + (size_t)(t0 + w*16 + rg + q)*CHUNK + (s0 + j*16 + col)] = acc[j][q];
  } else {
    // ---- fcd tall-skinny GEMM: FCD[4096x32] = XTb[:, :2048] @ fc_D_w^T ----
    ts_body_bf16(XTb, CONV_DIM, FCDWb, 2048, FCD, 32, 32, 2048,
                 (bidx - 832) * 16, (float*)smem);
  }
}

// ---------------- prefix-combine chunk states -> SPREV ----------------
__global__ __launch_bounds__(256) void state_combine_kernel(const float* __restrict__ SCH,
                                                            const float* __restrict__ CUMS,
                                                            float* __restrict__ SPREV) {
  int bid = blockIdx.x;
  int pq = bid & 3;
  int h = (bid >> 2) & 31;
  int r = bid >> 7;
  int tid = threadIdx.x;
  int p = pq*16 + (tid >> 4);
  int n = (tid & 15) * 4;
  float4 S = make_float4(0.f, 0.f, 0.f, 0.f);
  for (int c = 0; c < NCH; ++c) {
    size_t off = ((((size_t)r*NCH + c)*NHEADS + h)*HEADDIM + p)*D_STATE + n;
    *(float4*)(SPREV + off) = S;
    float dec = __expf(CUMS[((size_t)r*NHEADS + h)*SEQLEN + c*CHUNK + 255]);
    float4 v = *(const float4*)(SCH + off);
    S.x = dec*S.x + v.x; S.y = dec*S.y + v.y;
    S.z = dec*S.z + v.z; S.w = dec*S.w + v.w;
  }
}

// ---------------- Y = intra(triangular, MFMA) + inter (MFMA, fwd only), bf16 out ----------------
#define YS_ED(S0)                                                              \
  float edv[8];                                                                \
  { float4 e0_ = *(const float4*)&ecd[(S0) + kq];                              \
    float4 e1_ = *(const float4*)&ecd[(S0) + kq + 4];                          \
    edv[0]=e0_.x; edv[1]=e0_.y; edv[2]=e0_.z; edv[3]=e0_.w;                    \
    edv[4]=e1_.x; edv[5]=e1_.y; edv[6]=e1_.z; edv[7]=e1_.w; }

#define YS_BFR(S0)                                                             \
  short8 bfr[4];                                                               \
  _Pragma("unroll")                                                            \
  for (int j = 0; j < 4; ++j) {                                                \
    int R = j * 16 + fr;                                                       \
    bfr[j] = *(const short8*)&Xt[R * 264 + (((S0) + kq) ^ (((R >> 3) & 7) << 3))]; \
  }

#define YS_MFMA4(AF, ACCROW)                                                   \
  _Pragma("unroll")                                                            \
  for (int j = 0; j < 4; ++j)                                                  \
    ACCROW[j] = __builtin_amdgcn_mfma_f32_16x16x32_bf16(AF, bfr[j], ACCROW[j], 0, 0, 0);

#define YS_AF_NOMASK(C0, C1, E)                                                \
  { af_.u[0] = cvtpk_bf16(C0.x*(E)*edv[0], C0.y*(E)*edv[1]);                   \
    af_.u[1] = cvtpk_bf16(C0.z*(E)*edv[2], C0.w*(E)*edv[3]);                   \
    af_.u[2] = cvtpk_bf16(C1.x*(E)*edv[4], C1.y*(E)*edv[5]);                   \
    af_.u[3] = cvtpk_bf16(C1.z*(E)*edv[6], C1.w*(E)*edv[7]); }

#define YS_AF_MASK(C0, C1, E, TROW)                                            \
  { float wz[8] = {C0.x,C0.y,C0.z,C0.w,C1.x,C1.y,C1.z,C1.w};                   \
    _Pragma("unroll")                                                          \
    for (int jj = 0; jj < 8; ++jj) {                                           \
      float t_ = wz[jj]*(E)*edv[jj];                                           \
      wz[jj] = (kq + jj <= (TROW)) ? t_ : 0.f; }                               \
    af_.u[0]=cvtpk_bf16(wz[0],wz[1]); af_.u[1]=cvtpk_bf16(wz[2],wz[3]);        \
    af_.u[2]=cvtpk_bf16(wz[4],wz[5]); af_.u[3]=cvtpk_bf16(wz[6],wz[7]); }

#define YS_STRIP(KS, E2, ACC)                                                  \
  {                                                                            \
    const int t0s_ = (KS) * 32;                                                \
    const float* cbr0 = CBs + cbbase + (size_t)(t0s_ + fr) * CHUNK + kq;       \
    const float* cbr1 = cbr0 + (size_t)16 * CHUNK;                             \
    float4 a0 = *(const float4*)cbr0;                                          \
    float4 a1 = *(const float4*)(cbr0 + 4);                                    \
    float4 b0 = *(const float4*)cbr1;                                          \
    float4 b1 = *(const float4*)(cbr1 + 4);                                    \
    for (int sl = 0; sl < (KS); ++sl) {                                        \
      int s0 = sl * 32;                                                        \
      float4 na0 = *(const float4*)(cbr0 + s0 + 32);                           \
      float4 na1 = *(const float4*)(cbr0 + s0 + 36);                           \
      float4 nb0 = *(const float4*)(cbr1 + s0 + 32);                           \
      float4 nb1 = *(const float4*)(cbr1 + s0 + 36);                           \
      YS_ED(s0); YS_BFR(s0);                                                   \
      s8u af_;                                                                 \
      YS_AF_NOMASK(a0, a1, (E2)[0]);                                           \
      YS_MFMA4(af_.v, ACC[0]);                                                 \
      YS_AF_NOMASK(b0, b1, (E2)[1]);                                           \
      YS_MFMA4(af_.v, ACC[1]);                                                 \
      a0 = na0; a1 = na1; b0 = nb0; b1 = nb1;                                  \
    }                                                                          \
    {                                                                          \
      int s0 = (KS) * 32;                                                      \
      YS_ED(s0); YS_BFR(s0);                                                   \
      s8u af_;                                                                 \
      YS_AF_MASK(a0, a1, (E2)[0], fr);                                         \
      YS_MFMA4(af_.v, ACC[0]);                                                 \
      YS_AF_MASK(b0, b1, (E2)[1], 16 + fr);                                    \
      YS_MFMA4(af_.v, ACC[1]);                                                 \
    }                                                                          \
  }

#define YS_INTER(T0S, E2, ACC)                                                 \
  _Pragma("unroll")                                                            \
  for (int i = 0; i < 2; ++i) {                                                \
    int t = (T0S) + i * 16 + fr;                                               \
    const unsigned short* crow = XTb + ((size_t)bi*SEQLEN + c*CHUNK + t)*CONV_DIM + D_INNER + GN + n0 + kq; \
    ushort4 c0 = *(const ushort4*)crow;                                        \
    ushort4 c1 = *(const ushort4*)(crow + 4);                                  \
    float eI = (E2)[i];                                                        \
    s8u af_;                                                                   \
    af_.u[0] = cvtpk_bf16(bf2f(c0.x)*eI, bf2f(c0.y)*eI);                       \
    af_.u[1] = cvtpk_bf16(bf2f(c0.z)*eI, bf2f(c0.w)*eI);                       \
    af_.u[2] = cvtpk_bf16(bf2f(c1.x)*eI, bf2f(c1.y)*eI);                       \
    af_.u[3] = cvtpk_bf16(bf2f(c1.z)*eI, bf2f(c1.w)*eI);                       \
    YS_MFMA4(af_.v, ACC[i]);                                                   \
  }

#define YS_EPI(T0S, ACC)                                                       \
  _Pragma("unroll")                                                            \
  for (int i = 0; i < 2; ++i) {                                                \
    _Pragma("unroll")                                                          \
    for (int q = 0; q < 4; ++q)                                                \
      _Pragma("unroll")                                                        \
      for (int j = 0; j < 4; ++j)                                              \
        Ew[(rg + q) * 64 + j * 16 + fr] = f2bf(ACC[i][j][q]);                  \
    ushort8v v0 = *(const ushort8v*)&Ew[rr * 64 + c8];                         \
    ushort8v v1 = *(const ushort8v*)&Ew[(rr + 8) * 64 + c8];                   \
    *(ushort8v*)(Yb16 + ybase + (size_t)((T0S) + i*16 + rr) * D_INNER + c8) = v0;      \
    *(ushort8v*)(Yb16 + ybase + (size_t)((T0S) + i*16 + rr + 8) * D_INNER + c8) = v1;  \
  }

__global__ __launch_bounds__(256, 4) void yscan_kernel(const unsigned short* __restrict__ XTb,
                                                       const float* __restrict__ DTt,
                                                       const float* __restrict__ CUMS,
                                                       const float* __restrict__ CBs,
                                                       const float* __restrict__ SPREV,
                                                       unsigned short* __restrict__ Yb16) {
  __shared__ unsigned short Xt[64 * 264];   // X^T, swizzled columns (33792 B)
  __shared__ float cums[CHUNK];
  __shared__ float ecd[CHUNK];              // exp(-cum[s]) * dt[s]
  int tid = threadIdx.x;
  int lane = tid & 63;
  int w = tid >> 6;
  // XCD-clustered decode: id = c + 8*h + 256*r
  int id = blockIdx.x;
  int c = id & 7;
  int h = (id >> 3) & 31;
  int r = id >> 8;
  int rh = r * NHEADS + h;
  int bi = r & 1;
  // ---- stage: full X^T tile + cums + ecd, one barrier ----
  {
    int sr = tid >> 3;                 // 0..31
    int p0 = (tid & 7) * 8;            // 0..56
    int swz = (tid & 7) << 3;          // col-swizzle for p-block (p>>3 const over q)
#pragma unroll
    for (int P = 0; P < 8; ++P) {
      int s = P * 32 + sr;
      int L = c * CHUNK + s;
      if (r >= 2) L = flip_l(L);
      ushort8v v = *(const ushort8v*)(XTb + ((size_t)bi * SEQLEN + L) * CONV_DIM + h * HEADDIM + p0);
      int cswz = s ^ swz;
#pragma unroll
      for (int q = 0; q < 8; ++q)
        Xt[(p0 + q) * 264 + cswz] = v[q];
    }
    float cv = CUMS[(size_t)rh * SEQLEN + c * CHUNK + tid];
    cums[tid] = cv;
    ecd[tid] = __expf(-cv) * DTt[(size_t)rh * SEQLEN + c * CHUNK + tid];
  }
  __syncthreads();
  const int fr = lane & 15;
  const int kq = (lane >> 4) * 8;
  // balanced strips: wave w owns 32-row t-strips kA=w and kB=7-w
  const int kA = w, kB = 7 - w;
  const int tA = kA * 32, tB = kB * 32;
  float eAr[2], eBr[2];
#pragma unroll
  for (int i = 0; i < 2; ++i) {
    eAr[i] = __expf(cums[tA + i * 16 + fr]);
    eBr[i] = __expf(cums[tB + i * 16 + fr]);
  }
  floatx4 accA[2][4] = {};
  floatx4 accB[2][4] = {};
  size_t cbbase = (((size_t)r * NCH + c) * CHUNK) * CHUNK;
  YS_STRIP(kA, eAr, accA);
  YS_STRIP(kB, eBr, accB);
  if (r < 2) {
    const float* spbase = SPREV + (((size_t)r*NCH + c)*NHEADS + h) * (size_t)(HEADDIM*D_STATE);
#pragma unroll
    for (int ns = 0; ns < 2; ++ns) {
      int n0 = ns * 32;
      short8 bfr[4];
#pragma unroll
      for (int j = 0; j < 4; ++j) {
        const float* sp = spbase + (size_t)(j*16 + fr)*D_STATE + n0 + kq;
        float4 s0v = *(const float4*)sp;
        float4 s1v = *(const float4*)(sp + 4);
        s8u bb;
        bb.u[0] = cvtpk_bf16(s0v.x, s0v.y);
        bb.u[1] = cvtpk_bf16(s0v.z, s0v.w);
        bb.u[2] = cvtpk_bf16(s1v.x, s1v.y);
        bb.u[3] = cvtpk_bf16(s1v.z, s1v.w);
        bfr[j] = bb.v;
      }
      YS_INTER(tA, eAr, accA);
      YS_INTER(tB, eBr, accB);
    }
  }
  // bf16 epilogue: per-wave LDS transpose scratch inside Xt (barrier: Xt reads done)
  __syncthreads();
  unsigned short* Ew = Xt + w * 1024;
  const int rg = (lane >> 4) * 4;
  const int rr = lane >> 3;
  const int c8 = (lane & 7) * 8;
  size_t ybase = ((size_t)r*SEQLEN + c*CHUNK)*D_INNER + h*HEADDIM;
  YS_EPI(tA, accA);
  YS_EPI(tB, accB);
}

// ---------------- shifts + x_res + RMSNorm + gate (vectorized, -> bf16) ----------------
__global__ __launch_bounds__(256) void combine_kernel(const unsigned short* __restrict__ Y,
                                                      const unsigned short* __restrict__ XTb,
                                                      const float* __restrict__ FCD,
                                                      const float* __restrict__ Dp,
                                                      const unsigned short* __restrict__ Zb,
                                                      const float* __restrict__ norm_w,
                                                      unsigned short* __restrict__ YPb) {
  __shared__ float red4[4];
  int row = blockIdx.x;
  int bi = row >> 11;
  int l = row & 2047;
  int s = l >> 3, fr = l & 7;
  int tid = threadIdx.x;
  int d0 = tid * 8;
  const unsigned short* yf = (l >= 1) ? Y + ((size_t)bi*SEQLEN + (l-1))*D_INNER + d0 : nullptr;
  const unsigned short* yr = (s >= 1) ? Y + ((size_t)(2+bi)*SEQLEN + ((s-1)*8 + (7-fr)))*D_INNER + d0 : nullptr;
  const unsigned short* xr = XTb + ((size_t)row)*CONV_DIM + d0;
  float fcv = FCD[(size_t)row*NHEADS + (d0 >> 6)] + Dp[d0 >> 6];
  ushort8v xv8 = *(const ushort8v*)xr;
  float v[8];
#pragma unroll
  for (int q = 0; q < 8; ++q) v[q] = bf2f(xv8[q]) * fcv;
  if (yf) {
    ushort8v a = *(const ushort8v*)yf;
#pragma unroll
    for (int q = 0; q < 8; ++q) v[q] += bf2f(a[q]);
  }
  if (yr) {
    ushort8v a = *(const ushort8v*)yr;
#pragma unroll
    for (int q = 0; q < 8; ++q) v[q] += bf2f(a[q]);
  }
  float ss = 0.f;
#pragma unroll
  for (int q = 0; q < 8; ++q) ss += v[q] * v[q];
#pragma unroll
  for (int d = 1; d < 64; d <<= 1) ss += __shfl_xor(ss, d, 64);
  if ((tid & 63) == 0) red4[tid >> 6] = ss;
  __syncthreads();
  float tot = red4[0] + red4[1] + red4[2] + red4[3];
  float rs = rsqrtf(tot / (float)D_INNER + 1e-5f);
  ushort8v zv8 = *(const ushort8v*)(Zb + ((size_t)row)*ZLD + d0);
  float4 nw0 = *(const float4*)(norm_w + d0);
  float4 nw1 = *(const float4*)(norm_w + d0 + 4);
  float nw[8] = {nw0.x,nw0.y,nw0.z,nw0.w,nw1.x,nw1.y,nw1.z,nw1.w};
  ushort8v o;
#pragma unroll
  for (int q = 0; q < 8; ++q)
    o[q] = f2bf(v[q] * rs * nw[q] * silu_f(bf2f(zv8[q])));
  *(ushort8v*)(YPb + (size_t)row*D_INNER + d0) = o;
}

extern "C" void kernel_launch(void* const* d_in, const int* in_sizes, int n_in,
                              void* d_out, int out_size, void* d_ws, size_t ws_size,
                              hipStream_t stream) {
  (void)in_sizes; (void)n_in; (void)out_size; (void)ws_size;
  const float* u          = (const float*)d_in[0];
  const float* in_proj_w  = (const float*)d_in[1];
  const float* conv_sp_w  = (const float*)d_in[2];
  const float* conv_sp_b  = (const float*)d_in[3];
  const float* conv_tp_w  = (const float*)d_in[4];
  const float* conv_tp_b  = (const float*)d_in[5];
  const float* dt_bias    = (const float*)d_in[6];
  const float* A_log      = (const float*)d_in[7];
  const float* Dp         = (const float*)d_in[8];
  const float* fc_D_w     = (const float*)d_in[9];
  const float* norm_w     = (const float*)d_in[10];
  const float* out_proj_w = (const float*)d_in[11];
  float* out = (float*)d_out;
  float* ws = (float*)d_ws;

  // workspace layout (f32-element offsets; Z/XT/Y regions hold bf16)
  float* Z     = ws;                       // 17,825,792 slots (bf16 uses half)
  float* SH    = Z     + 17825792ULL;      // 9,437,184  (CBs -> YPb)
  float* XT    = SH    + 9437184ULL;       // 9,437,184  (bf16 uses half)
  float* DTt   = XT    + 9437184ULL;       // 262,144
  float* Yb    = DTt   + 262144ULL;        // 16,777,216 (bf16 Y in first half; SCH; Wob/FCDWb tail)
  float* SPREV = Yb    + 16777216ULL;      // 2,097,152
  float* FCD   = SPREV + 2097152ULL;       // 131,072
  float* DTraw = FCD   + 131072ULL;        // 262,144
  float* CUMS  = DTraw + 262144ULL;        // 262,144

  unsigned short* Zb   = (unsigned short*)Z;
  unsigned short* XTb  = (unsigned short*)XT;
  unsigned short* Yb16 = (unsigned short*)Yb;            // floats [0, 8,388,608)
  unsigned short* Ub   = (unsigned short*)Yb;            // staging (dead before yscan)
  unsigned short* Wb   = (unsigned short*)Yb + 4194304ULL;   // 4416x1024 ushorts (incl. dt rows)
  float* SCH = Yb + 8388608ULL;                          // floats [8,388,608, 10,485,760)
  unsigned short* Wob = (unsigned short*)(Yb + 10485760ULL); // out_proj bf16, 1024x2048
  unsigned short* FCDWb = (unsigned short*)(Yb + 11534336ULL); // fc_D_w bf16, 32x2048
  unsigned short* YPb = (unsigned short*)SH;

  cast4_bf16_kernel<<<10624, 256, 0, stream>>>(u, Ub, 4096, in_proj_w, Wb, 4416,
                                               out_proj_w, Wob, 2048, fc_D_w, FCDWb);
  gemm_main_kernel<<<dim3(1344), 256, 0, stream>>>(Ub, 1024, Wb, 1024, Zb, ZLD, 1024,
                                                   Wb + 4352ULL*1024, DTraw);
  fused_dtconv_kernel<<<2176, 256, 0, stream>>>(DTraw, dt_bias, A_log, DTt, CUMS,
                                                Zb, conv_sp_w, conv_sp_b,
                                                conv_tp_w, conv_tp_b, XTb);
  fused_post_kernel<<<1088, 256, 0, stream>>>(XTb, DTt, CUMS, SH, SCH, FCDWb, FCD);
  state_combine_kernel<<<256, 256, 0, stream>>>(SCH, CUMS, SPREV);
  yscan_kernel<<<dim3(1024), 256, 0, stream>>>(XTb, DTt, CUMS, SH, SPREV, Yb16);
  combine_kernel<<<4096, 256, 0, stream>>>(Yb16, XTb, FCD, Dp, Zb, norm_w, YPb);
  gemm_m64_f32<<<dim3(512), 256, 0, stream>>>(YPb, 2048, Wob, 2048, out, 1024, 2048);
}